// Round 3
// baseline (4311.100 us; speedup 1.0000x reference)
//
#include <hip/hip_runtime.h>
#include <hip/hip_bf16.h>

#define F 64

// Combined weight Wc[256][64] f32 (factorization of concat([h+r,h*r,h,r])@W):
//   rows 0..63  : A = W0+W2   (multiplies mean_h)
//   rows 64..127: B = W0+W3   (multiplies mean_r)
//   rows 128..191: W1         (multiplies mean_{h*r})
//   rows 192..255: loop_weight (multiplies feat)
__global__ void k_prep(const float* __restrict__ wn, const float* __restrict__ lw,
                       float* __restrict__ wc) {
    int i = blockIdx.x * 256 + threadIdx.x;   // 0..16383
    int k = i >> 6, j = i & 63;
    float v;
    if (k < 64)
        v = wn[k * 64 + j] + wn[(128 + k) * 64 + j];
    else if (k < 128)
        v = wn[(k - 64) * 64 + j] + wn[(k + 128) * 64 + j];
    else if (k < 192)
        v = wn[(k - 64) * 64 + j];            // W1 row (k-128) = wn row 64+(k-128)
    else
        v = lw[(k - 192) * 64 + j];
    wc[i] = v;
}

__global__ void k_hist(const int* __restrict__ dst, int* __restrict__ cnt, int e) {
    int i = blockIdx.x * blockDim.x + threadIdx.x;
    if (i < e) atomicAdd(&cnt[dst[i]], 1);
}

// Single-block exclusive scan: cnt[0..n) -> off[0..n] and cursor copy.
__global__ void k_scan(const int* __restrict__ cnt, int* __restrict__ off,
                       int* __restrict__ cursor, int n) {
    __shared__ int sd[1024];
    int tid = threadIdx.x;
    int chunk = (n + 1023) >> 10;
    int s0 = tid * chunk;
    int s1 = s0 + chunk; if (s1 > n) s1 = n; if (s0 > n) s0 = n;
    int sum = 0;
    for (int i = s0; i < s1; ++i) sum += cnt[i];
    sd[tid] = sum;
    __syncthreads();
    for (int s = 1; s < 1024; s <<= 1) {
        int t = (tid >= s) ? sd[tid - s] : 0;
        __syncthreads();
        sd[tid] += t;
        __syncthreads();
    }
    int run = sd[tid] - sum;   // exclusive prefix of this thread's chunk
    for (int i = s0; i < s1; ++i) {
        off[i] = run; cursor[i] = run; run += cnt[i];
    }
    if (tid == 1023) off[n] = sd[1023];
}

__global__ void k_scatter(const int* __restrict__ src, const int* __restrict__ dst,
                          const int* __restrict__ et, int* __restrict__ cursor,
                          unsigned int* __restrict__ bucket, int e) {
    int i = blockIdx.x * blockDim.x + threadIdx.x;
    if (i < e) {
        int p = atomicAdd(&cursor[dst[i]], 1);
        bucket[p] = (unsigned int)src[i] | ((unsigned int)et[i] << 16);  // src<65536, et<65536
    }
}

// One wave per 8 nodes; lane = feature index.
// Phase A: per node accumulate S_h, S_r, S_hr over incoming edges (f32 regs).
// Phase B: out[v][lane] = sum_k x[v][k] * Wc[k][lane] via lane broadcasts.
__global__ __launch_bounds__(256) void k_main(
    const float* __restrict__ feat, const float* __restrict__ rel,
    const float* __restrict__ wc, const int* __restrict__ off,
    const unsigned int* __restrict__ bucket,
    float* __restrict__ out, int n_nodes) {

    const int lane = threadIdx.x & 63;
    const int wid  = threadIdx.x >> 6;
    const int node0 = (blockIdx.x * 4 + wid) * 8;

    float aH[8], aR[8], aHR[8], fv[8], acc[8];
#pragma unroll
    for (int n = 0; n < 8; ++n) { aH[n]=0.f; aR[n]=0.f; aHR[n]=0.f; fv[n]=0.f; acc[n]=0.f; }

#pragma unroll
    for (int n = 0; n < 8; ++n) {
        int v = node0 + n;
        if (v < n_nodes) {
            int o0 = off[v], o1 = off[v + 1];
            float sH = 0.f, sR = 0.f, sHR = 0.f;
            for (int p = o0; p < o1; p += 64) {
                int m = o1 - p; if (m > 64) m = 64;
                unsigned int pk = (lane < m) ? bucket[p + lane] : 0u;
                for (int j = 0; j < m; ++j) {
                    unsigned int pj = __shfl(pk, j);
                    int s = (int)(pj & 0xFFFFu);
                    int t = (int)(pj >> 16);
                    float h = feat[s * F + lane];
                    float r = rel[t * F + lane];
                    sH += h; sR += r; sHR += h * r;
                }
            }
            int deg = o1 - o0;
            float inv = (deg > 0) ? 1.0f / (float)deg : 1.0f;
            aH[n] = sH * inv; aR[n] = sR * inv; aHR[n] = sHR * inv;
            fv[n] = feat[v * F + lane];
        }
    }

#pragma unroll
    for (int kk = 0; kk < 64; ++kk) {
        float w0 = wc[kk * F + lane];
        float w1 = wc[(64 + kk) * F + lane];
        float w2 = wc[(128 + kk) * F + lane];
        float w3 = wc[(192 + kk) * F + lane];
#pragma unroll
        for (int n = 0; n < 8; ++n) {
            acc[n] += __shfl(aH[n], kk) * w0 + __shfl(aR[n], kk) * w1
                    + __shfl(aHR[n], kk) * w2 + __shfl(fv[n], kk) * w3;
        }
    }

#pragma unroll
    for (int n = 0; n < 8; ++n) {
        int v = node0 + n;
        if (v < n_nodes) out[v * F + lane] = acc[n];
    }
}

extern "C" void kernel_launch(void* const* d_in, const int* in_sizes, int n_in,
                              void* d_out, int out_size, void* d_ws, size_t ws_size,
                              hipStream_t stream) {
    const float* feat = (const float*)d_in[0];
    const float* rel  = (const float*)d_in[1];
    const float* wn   = (const float*)d_in[2];
    const float* lw   = (const float*)d_in[3];
    const int* src = (const int*)d_in[4];
    const int* dst = (const int*)d_in[5];
    const int* et  = (const int*)d_in[6];
    float* out = (float*)d_out;

    const int N = in_sizes[0] / F;
    const int E = in_sizes[4];

    int* ws = (int*)d_ws;
    int* cnt             = ws;                            // N
    int* off             = cnt + N;                       // N+1
    int* cursor          = off + N + 1;                   // N
    unsigned int* bucket = (unsigned int*)(cursor + N);   // E
    float* wc            = (float*)(bucket + E);          // 16384

    hipMemsetAsync(cnt, 0, (size_t)N * sizeof(int), stream);
    k_prep<<<64, 256, 0, stream>>>(wn, lw, wc);
    k_hist<<<(E + 255) / 256, 256, 0, stream>>>(dst, cnt, E);
    k_scan<<<1, 1024, 0, stream>>>(cnt, off, cursor, N);
    k_scatter<<<(E + 255) / 256, 256, 0, stream>>>(src, dst, et, cursor, bucket, E);
    int blocks = (N + 31) / 32;   // 32 nodes/block (4 waves x 8 nodes)
    k_main<<<blocks, 256, 0, stream>>>(feat, rel, wc, off, bucket, out, N);
}

// Round 4
// 440.324 us; speedup vs baseline: 9.7907x; 9.7907x over previous
//
#include <hip/hip_runtime.h>
#include <hip/hip_bf16.h>

#define F 64
#define NPW 4   // nodes per wave; 4 waves/block -> 16 nodes/block

// Combined weight Wc[256][64] f32 (factorization of concat([h+r,h*r,h,r])@W):
//   rows 0..63  : W0+W2   (multiplies mean_h)
//   rows 64..127: W0+W3   (multiplies mean_r)
//   rows 128..191: W1     (multiplies mean_{h*r})
//   rows 192..255: loop_weight (multiplies feat)
__global__ void k_prep(const float* __restrict__ wn, const float* __restrict__ lw,
                       float* __restrict__ wc) {
    int i = blockIdx.x * 256 + threadIdx.x;   // 0..16383
    int k = i >> 6, j = i & 63;
    float v;
    if (k < 64)
        v = wn[k * 64 + j] + wn[(128 + k) * 64 + j];
    else if (k < 128)
        v = wn[(k - 64) * 64 + j] + wn[(k + 128) * 64 + j];
    else if (k < 192)
        v = wn[(k - 64) * 64 + j];            // W1 row (k-128) = wn row 64+(k-128)
    else
        v = lw[(k - 192) * 64 + j];
    wc[i] = v;
}

__global__ void k_hist(const int* __restrict__ dst, int* __restrict__ cnt, int e) {
    int i = blockIdx.x * blockDim.x + threadIdx.x;
    if (i < e) atomicAdd(&cnt[dst[i]], 1);
}

// Single-block exclusive scan: cnt[0..n) -> off[0..n] and cursor copy.
__global__ void k_scan(const int* __restrict__ cnt, int* __restrict__ off,
                       int* __restrict__ cursor, int n) {
    __shared__ int sd[1024];
    int tid = threadIdx.x;
    int chunk = (n + 1023) >> 10;
    int s0 = tid * chunk;
    int s1 = s0 + chunk; if (s1 > n) s1 = n; if (s0 > n) s0 = n;
    int sum = 0;
    for (int i = s0; i < s1; ++i) sum += cnt[i];
    sd[tid] = sum;
    __syncthreads();
    for (int s = 1; s < 1024; s <<= 1) {
        int t = (tid >= s) ? sd[tid - s] : 0;
        __syncthreads();
        sd[tid] += t;
        __syncthreads();
    }
    int run = sd[tid] - sum;
    for (int i = s0; i < s1; ++i) {
        off[i] = run; cursor[i] = run; run += cnt[i];
    }
    if (tid == 1023) off[n] = sd[1023];
}

__global__ void k_scatter(const int* __restrict__ src, const int* __restrict__ dst,
                          const int* __restrict__ et, int* __restrict__ cursor,
                          unsigned int* __restrict__ bucket, int e) {
    int i = blockIdx.x * blockDim.x + threadIdx.x;
    if (i < e) {
        int p = atomicAdd(&cursor[dst[i]], 1);
        bucket[p] = (unsigned int)src[i] | ((unsigned int)et[i] << 16);  // src,et < 65536
    }
}

// One wave per NPW nodes; lane = feature index.
// Phase A: accumulate S_h, S_r, S_hr per node; edge loop unrolled x4 so 8
//          independent gathers are in flight (hides L2/L3 latency).
// Phase B: out[v][lane] = sum_k x[v][k]*Wc[k][lane]; kk-loop unroll capped at 8
//          so the scheduler can't hoist all 256 wc loads (that spilled in R3:
//          VGPR=256, 2.8 GB scratch writes, 4 ms).
__global__ __launch_bounds__(256, 4) void k_main(
    const float* __restrict__ feat, const float* __restrict__ rel,
    const float* __restrict__ wc, const int* __restrict__ off,
    const unsigned int* __restrict__ bucket,
    float* __restrict__ out, int n_nodes) {

    const int lane = threadIdx.x & 63;
    const int wid  = threadIdx.x >> 6;
    const int node0 = (blockIdx.x * 4 + wid) * NPW;

    float aH[NPW], aR[NPW], aHR[NPW], fv[NPW], acc[NPW];
#pragma unroll
    for (int n = 0; n < NPW; ++n) { aH[n]=0.f; aR[n]=0.f; aHR[n]=0.f; fv[n]=0.f; acc[n]=0.f; }

#pragma unroll
    for (int n = 0; n < NPW; ++n) {
        int v = node0 + n;
        if (v < n_nodes) {
            int o0 = off[v], o1 = off[v + 1];
            float sH = 0.f, sR = 0.f, sHR = 0.f;
            for (int p = o0; p < o1; p += 64) {
                int m = o1 - p; if (m > 64) m = 64;
                unsigned int pk = (lane < m) ? bucket[p + lane] : 0u;
                int j = 0;
                for (; j + 4 <= m; j += 4) {
                    unsigned int u0 = __shfl(pk, j);
                    unsigned int u1 = __shfl(pk, j + 1);
                    unsigned int u2 = __shfl(pk, j + 2);
                    unsigned int u3 = __shfl(pk, j + 3);
                    float h0 = feat[(int)(u0 & 0xFFFFu) * F + lane];
                    float r0 = rel[(int)(u0 >> 16) * F + lane];
                    float h1 = feat[(int)(u1 & 0xFFFFu) * F + lane];
                    float r1 = rel[(int)(u1 >> 16) * F + lane];
                    float h2 = feat[(int)(u2 & 0xFFFFu) * F + lane];
                    float r2 = rel[(int)(u2 >> 16) * F + lane];
                    float h3 = feat[(int)(u3 & 0xFFFFu) * F + lane];
                    float r3 = rel[(int)(u3 >> 16) * F + lane];
                    sH += h0 + h1 + h2 + h3;
                    sR += r0 + r1 + r2 + r3;
                    sHR += h0 * r0 + h1 * r1 + h2 * r2 + h3 * r3;
                }
                for (; j < m; ++j) {
                    unsigned int u = __shfl(pk, j);
                    float h = feat[(int)(u & 0xFFFFu) * F + lane];
                    float r = rel[(int)(u >> 16) * F + lane];
                    sH += h; sR += r; sHR += h * r;
                }
            }
            int deg = o1 - o0;
            float inv = (deg > 0) ? 1.0f / (float)deg : 1.0f;
            aH[n] = sH * inv; aR[n] = sR * inv; aHR[n] = sHR * inv;
            fv[n] = feat[v * F + lane];
        }
    }

#pragma unroll 8
    for (int kk = 0; kk < 64; ++kk) {
        float w0 = wc[kk * F + lane];
        float w1 = wc[(64 + kk) * F + lane];
        float w2 = wc[(128 + kk) * F + lane];
        float w3 = wc[(192 + kk) * F + lane];
#pragma unroll
        for (int n = 0; n < NPW; ++n) {
            acc[n] += __shfl(aH[n], kk) * w0 + __shfl(aR[n], kk) * w1
                    + __shfl(aHR[n], kk) * w2 + __shfl(fv[n], kk) * w3;
        }
    }

#pragma unroll
    for (int n = 0; n < NPW; ++n) {
        int v = node0 + n;
        if (v < n_nodes) out[v * F + lane] = acc[n];
    }
}

extern "C" void kernel_launch(void* const* d_in, const int* in_sizes, int n_in,
                              void* d_out, int out_size, void* d_ws, size_t ws_size,
                              hipStream_t stream) {
    const float* feat = (const float*)d_in[0];
    const float* rel  = (const float*)d_in[1];
    const float* wn   = (const float*)d_in[2];
    const float* lw   = (const float*)d_in[3];
    const int* src = (const int*)d_in[4];
    const int* dst = (const int*)d_in[5];
    const int* et  = (const int*)d_in[6];
    float* out = (float*)d_out;

    const int N = in_sizes[0] / F;
    const int E = in_sizes[4];

    int* ws = (int*)d_ws;
    int* cnt             = ws;                            // N
    int* off             = cnt + N;                       // N+1
    int* cursor          = off + N + 1;                   // N
    unsigned int* bucket = (unsigned int*)(cursor + N);   // E
    float* wc            = (float*)(bucket + E);          // 16384

    hipMemsetAsync(cnt, 0, (size_t)N * sizeof(int), stream);
    k_prep<<<64, 256, 0, stream>>>(wn, lw, wc);
    k_hist<<<(E + 255) / 256, 256, 0, stream>>>(dst, cnt, E);
    k_scan<<<1, 1024, 0, stream>>>(cnt, off, cursor, N);
    k_scatter<<<(E + 255) / 256, 256, 0, stream>>>(src, dst, et, cursor, bucket, E);
    int blocks = (N + NPW * 4 - 1) / (NPW * 4);   // 16 nodes/block
    k_main<<<blocks, 256, 0, stream>>>(feat, rel, wc, off, bucket, out, N);
}

// Round 5
// 327.706 us; speedup vs baseline: 13.1554x; 1.3437x over previous
//
#include <hip/hip_runtime.h>
#include <hip/hip_bf16.h>

#define F 64
#define NPW 2   // nodes per wave; 4 waves/block -> 8 nodes/block

// Combined weight Wc[256][64] f32 (factorization of concat([h+r,h*r,h,r])@W):
//   rows 0..63  : W0+W2   (multiplies mean_h)
//   rows 64..127: W0+W3   (multiplies mean_r)
//   rows 128..191: W1     (multiplies mean_{h*r})
//   rows 192..255: loop_weight (multiplies feat)
__global__ void k_prep(const float* __restrict__ wn, const float* __restrict__ lw,
                       float* __restrict__ wc) {
    int i = blockIdx.x * 256 + threadIdx.x;   // 0..16383
    int k = i >> 6, j = i & 63;
    float v;
    if (k < 64)
        v = wn[k * 64 + j] + wn[(128 + k) * 64 + j];
    else if (k < 128)
        v = wn[(k - 64) * 64 + j] + wn[(k + 128) * 64 + j];
    else if (k < 192)
        v = wn[(k - 64) * 64 + j];            // W1 row (k-128) = wn row 64+(k-128)
    else
        v = lw[(k - 192) * 64 + j];
    wc[i] = v;
}

__global__ void k_hist(const int* __restrict__ dst, int* __restrict__ cnt, int e) {
    int i = blockIdx.x * blockDim.x + threadIdx.x;
    if (i < e) atomicAdd(&cnt[dst[i]], 1);
}

// --- coalesced 3-kernel scan (replaces R4's single-block strided scan, whose
//     196B-lane-stride pattern hit ~196 cache lines per wave instr on 1 CU) ---

// Per-1024-element block sums, coalesced.
__global__ void k_bsum(const int* __restrict__ cnt, int* __restrict__ bsum, int n) {
    __shared__ int sd[256];
    int b = blockIdx.x, t = threadIdx.x;
    int base = b * 1024;
    int s = 0;
#pragma unroll
    for (int k = 0; k < 4; ++k) {
        int i = base + k * 256 + t;
        if (i < n) s += cnt[i];
    }
    sd[t] = s;
    __syncthreads();
    for (int st = 128; st > 0; st >>= 1) {
        if (t < st) sd[t] += sd[t + st];
        __syncthreads();
    }
    if (t == 0) bsum[b] = sd[0];
}

// Exclusive scan of nb block sums (nb<=64 fast path: one wave shfl-scan).
__global__ void k_bscan(const int* __restrict__ bsum, int* __restrict__ bbase,
                        int* __restrict__ off, int nb, int n) {
    int lane = threadIdx.x;
    if (nb <= 64) {
        int own = (lane < nb) ? bsum[lane] : 0;
        int v = own;
        for (int d = 1; d < 64; d <<= 1) {
            int w = __shfl_up(v, d);
            if (lane >= d) v += w;
        }
        if (lane < nb) bbase[lane] = v - own;   // exclusive
        if (lane == 63) off[n] = v;             // grand total
    } else if (lane == 0) {                     // safety fallback
        int run = 0;
        for (int i = 0; i < nb; ++i) { bbase[i] = run; run += bsum[i]; }
        off[n] = run;
    }
}

// Per-block scan: int4 loads, LDS Hillis-Steele over 256 partials, int4 stores.
__global__ void k_off(const int* __restrict__ cnt, const int* __restrict__ bbase,
                      int* __restrict__ off, int* __restrict__ cursor, int n) {
    __shared__ int sd[256];
    int b = blockIdx.x, t = threadIdx.x;
    int i0 = b * 1024 + 4 * t;
    int c0 = 0, c1 = 0, c2 = 0, c3 = 0;
    if (i0 + 3 < n) {
        int4 q = *(const int4*)(cnt + i0);
        c0 = q.x; c1 = q.y; c2 = q.z; c3 = q.w;
    } else {
        if (i0     < n) c0 = cnt[i0];
        if (i0 + 1 < n) c1 = cnt[i0 + 1];
        if (i0 + 2 < n) c2 = cnt[i0 + 2];
        if (i0 + 3 < n) c3 = cnt[i0 + 3];
    }
    int s = c0 + c1 + c2 + c3;
    sd[t] = s;
    __syncthreads();
    for (int d = 1; d < 256; d <<= 1) {
        int w = (t >= d) ? sd[t - d] : 0;
        __syncthreads();
        sd[t] += w;
        __syncthreads();
    }
    int o0 = sd[t] - s + bbase[b];
    int o1 = o0 + c0, o2 = o1 + c1, o3 = o2 + c2;
    if (i0 + 3 < n) {
        int4 q = make_int4(o0, o1, o2, o3);
        *(int4*)(off + i0) = q;
        *(int4*)(cursor + i0) = q;
    } else {
        if (i0     < n) { off[i0]     = o0; cursor[i0]     = o0; }
        if (i0 + 1 < n) { off[i0 + 1] = o1; cursor[i0 + 1] = o1; }
        if (i0 + 2 < n) { off[i0 + 2] = o2; cursor[i0 + 2] = o2; }
        if (i0 + 3 < n) { off[i0 + 3] = o3; cursor[i0 + 3] = o3; }
    }
}

__global__ void k_scatter(const int* __restrict__ src, const int* __restrict__ dst,
                          const int* __restrict__ et, int* __restrict__ cursor,
                          unsigned int* __restrict__ bucket, int e) {
    int i = blockIdx.x * blockDim.x + threadIdx.x;
    if (i < e) {
        int p = atomicAdd(&cursor[dst[i]], 1);
        bucket[p] = (unsigned int)src[i] | ((unsigned int)et[i] << 16);  // src,et < 65536
    }
}

// One wave per NPW nodes; lane = feature index.
// Phase A: accumulate S_h, S_r, S_hr per node; edge loop unrolled x8 (16
//          independent gathers in flight — latency-bound per R4 counters:
//          VALUBusy 27%, HBM 14%, ~0.3 L1 lines/cyc).
// Phase B: out[v][lane] = sum_k x[v][k]*Wc[k][lane]; kk-unroll capped at 8
//          (full unroll spilled in R3: VGPR=256, 2.8 GB scratch, 4 ms).
__global__ __launch_bounds__(256, 4) void k_main(
    const float* __restrict__ feat, const float* __restrict__ rel,
    const float* __restrict__ wc, const int* __restrict__ off,
    const unsigned int* __restrict__ bucket,
    float* __restrict__ out, int n_nodes) {

    const int lane = threadIdx.x & 63;
    const int wid  = threadIdx.x >> 6;
    const int node0 = (blockIdx.x * 4 + wid) * NPW;

    float aH[NPW], aR[NPW], aHR[NPW], fv[NPW], acc[NPW];
#pragma unroll
    for (int n = 0; n < NPW; ++n) { aH[n]=0.f; aR[n]=0.f; aHR[n]=0.f; fv[n]=0.f; acc[n]=0.f; }

#pragma unroll
    for (int n = 0; n < NPW; ++n) {
        int v = node0 + n;
        if (v < n_nodes) {
            int o0 = off[v], o1 = off[v + 1];
            float sH = 0.f, sR = 0.f, sHR = 0.f;
            for (int p = o0; p < o1; p += 64) {
                int m = o1 - p; if (m > 64) m = 64;
                unsigned int pk = (lane < m) ? bucket[p + lane] : 0u;
                int j = 0;
                for (; j + 8 <= m; j += 8) {
                    unsigned int u0 = __shfl(pk, j);
                    unsigned int u1 = __shfl(pk, j + 1);
                    unsigned int u2 = __shfl(pk, j + 2);
                    unsigned int u3 = __shfl(pk, j + 3);
                    unsigned int u4 = __shfl(pk, j + 4);
                    unsigned int u5 = __shfl(pk, j + 5);
                    unsigned int u6 = __shfl(pk, j + 6);
                    unsigned int u7 = __shfl(pk, j + 7);
                    float h0 = feat[(int)(u0 & 0xFFFFu) * F + lane];
                    float r0 = rel[(int)(u0 >> 16) * F + lane];
                    float h1 = feat[(int)(u1 & 0xFFFFu) * F + lane];
                    float r1 = rel[(int)(u1 >> 16) * F + lane];
                    float h2 = feat[(int)(u2 & 0xFFFFu) * F + lane];
                    float r2 = rel[(int)(u2 >> 16) * F + lane];
                    float h3 = feat[(int)(u3 & 0xFFFFu) * F + lane];
                    float r3 = rel[(int)(u3 >> 16) * F + lane];
                    float h4 = feat[(int)(u4 & 0xFFFFu) * F + lane];
                    float r4 = rel[(int)(u4 >> 16) * F + lane];
                    float h5 = feat[(int)(u5 & 0xFFFFu) * F + lane];
                    float r5 = rel[(int)(u5 >> 16) * F + lane];
                    float h6 = feat[(int)(u6 & 0xFFFFu) * F + lane];
                    float r6 = rel[(int)(u6 >> 16) * F + lane];
                    float h7 = feat[(int)(u7 & 0xFFFFu) * F + lane];
                    float r7 = rel[(int)(u7 >> 16) * F + lane];
                    sH += ((h0 + h1) + (h2 + h3)) + ((h4 + h5) + (h6 + h7));
                    sR += ((r0 + r1) + (r2 + r3)) + ((r4 + r5) + (r6 + r7));
                    sHR += h0 * r0 + h1 * r1 + h2 * r2 + h3 * r3
                         + h4 * r4 + h5 * r5 + h6 * r6 + h7 * r7;
                }
                for (; j < m; ++j) {
                    unsigned int u = __shfl(pk, j);
                    float h = feat[(int)(u & 0xFFFFu) * F + lane];
                    float r = rel[(int)(u >> 16) * F + lane];
                    sH += h; sR += r; sHR += h * r;
                }
            }
            int deg = o1 - o0;
            float inv = (deg > 0) ? 1.0f / (float)deg : 1.0f;
            aH[n] = sH * inv; aR[n] = sR * inv; aHR[n] = sHR * inv;
            fv[n] = feat[v * F + lane];
        }
    }

#pragma unroll 8
    for (int kk = 0; kk < 64; ++kk) {
        float w0 = wc[kk * F + lane];
        float w1 = wc[(64 + kk) * F + lane];
        float w2 = wc[(128 + kk) * F + lane];
        float w3 = wc[(192 + kk) * F + lane];
#pragma unroll
        for (int n = 0; n < NPW; ++n) {
            acc[n] += __shfl(aH[n], kk) * w0 + __shfl(aR[n], kk) * w1
                    + __shfl(aHR[n], kk) * w2 + __shfl(fv[n], kk) * w3;
        }
    }

#pragma unroll
    for (int n = 0; n < NPW; ++n) {
        int v = node0 + n;
        if (v < n_nodes) out[v * F + lane] = acc[n];
    }
}

extern "C" void kernel_launch(void* const* d_in, const int* in_sizes, int n_in,
                              void* d_out, int out_size, void* d_ws, size_t ws_size,
                              hipStream_t stream) {
    const float* feat = (const float*)d_in[0];
    const float* rel  = (const float*)d_in[1];
    const float* wn   = (const float*)d_in[2];
    const float* lw   = (const float*)d_in[3];
    const int* src = (const int*)d_in[4];
    const int* dst = (const int*)d_in[5];
    const int* et  = (const int*)d_in[6];
    float* out = (float*)d_out;

    const int N = in_sizes[0] / F;
    const int E = in_sizes[4];
    const int NB = (N + 1023) / 1024;   // scan blocks (49 for N=50000)

    int* ws = (int*)d_ws;
    int* cnt             = ws;                            // N
    int* off             = cnt + N;                       // N+1
    int* cursor          = off + N + 1;                   // N
    int* bsum            = cursor + N;                    // NB
    int* bbase           = bsum + NB;                     // NB
    unsigned int* bucket = (unsigned int*)(bbase + NB);   // E
    float* wc            = (float*)(bucket + E);          // 16384

    hipMemsetAsync(cnt, 0, (size_t)N * sizeof(int), stream);
    k_prep<<<64, 256, 0, stream>>>(wn, lw, wc);
    k_hist<<<(E + 255) / 256, 256, 0, stream>>>(dst, cnt, E);
    k_bsum<<<NB, 256, 0, stream>>>(cnt, bsum, N);
    k_bscan<<<1, 64, 0, stream>>>(bsum, bbase, off, NB, N);
    k_off<<<NB, 256, 0, stream>>>(cnt, bbase, off, cursor, N);
    k_scatter<<<(E + 255) / 256, 256, 0, stream>>>(src, dst, et, cursor, bucket, E);
    int blocks = (N + NPW * 4 - 1) / (NPW * 4);   // 8 nodes/block
    k_main<<<blocks, 256, 0, stream>>>(feat, rel, wc, off, bucket, out, N);
}

// Round 6
// 317.841 us; speedup vs baseline: 13.5637x; 1.0310x over previous
//
#include <hip/hip_runtime.h>
#include <hip/hip_bf16.h>

#define F 64
#define NPW 2   // nodes per wave; 4 waves/block -> 8 nodes/block

// Combined weight Wc[256][64] f32 (factorization of concat([h+r,h*r,h,r])@W):
//   rows 0..63  : W0+W2   (multiplies mean_h)
//   rows 64..127: W0+W3   (multiplies mean_r)
//   rows 128..191: W1     (multiplies mean_{h*r})
//   rows 192..255: loop_weight (multiplies feat)
__global__ void k_prep(const float* __restrict__ wn, const float* __restrict__ lw,
                       float* __restrict__ wc) {
    int i = blockIdx.x * 256 + threadIdx.x;   // 0..16383
    int k = i >> 6, j = i & 63;
    float v;
    if (k < 64)
        v = wn[k * 64 + j] + wn[(128 + k) * 64 + j];
    else if (k < 128)
        v = wn[(k - 64) * 64 + j] + wn[(k + 128) * 64 + j];
    else if (k < 192)
        v = wn[(k - 64) * 64 + j];            // W1 row (k-128) = wn row 64+(k-128)
    else
        v = lw[(k - 192) * 64 + j];
    wc[i] = v;
}

// 4 edges per thread (int4), halves wave count vs R5.
__global__ void k_hist(const int* __restrict__ dst, int* __restrict__ cnt, int e4) {
    int i = blockIdx.x * blockDim.x + threadIdx.x;
    if (i < e4) {
        int4 d = ((const int4*)dst)[i];
        atomicAdd(&cnt[d.x], 1);
        atomicAdd(&cnt[d.y], 1);
        atomicAdd(&cnt[d.z], 1);
        atomicAdd(&cnt[d.w], 1);
    }
}

// --- coalesced 3-kernel scan ---
__global__ void k_bsum(const int* __restrict__ cnt, int* __restrict__ bsum, int n) {
    __shared__ int sd[256];
    int b = blockIdx.x, t = threadIdx.x;
    int base = b * 1024;
    int s = 0;
#pragma unroll
    for (int k = 0; k < 4; ++k) {
        int i = base + k * 256 + t;
        if (i < n) s += cnt[i];
    }
    sd[t] = s;
    __syncthreads();
    for (int st = 128; st > 0; st >>= 1) {
        if (t < st) sd[t] += sd[t + st];
        __syncthreads();
    }
    if (t == 0) bsum[b] = sd[0];
}

__global__ void k_bscan(const int* __restrict__ bsum, int* __restrict__ bbase,
                        int* __restrict__ off, int nb, int n) {
    int lane = threadIdx.x;
    if (nb <= 64) {
        int own = (lane < nb) ? bsum[lane] : 0;
        int v = own;
        for (int d = 1; d < 64; d <<= 1) {
            int w = __shfl_up(v, d);
            if (lane >= d) v += w;
        }
        if (lane < nb) bbase[lane] = v - own;   // exclusive
        if (lane == 63) off[n] = v;             // grand total
    } else if (lane == 0) {                     // safety fallback
        int run = 0;
        for (int i = 0; i < nb; ++i) { bbase[i] = run; run += bsum[i]; }
        off[n] = run;
    }
}

__global__ void k_off(const int* __restrict__ cnt, const int* __restrict__ bbase,
                      int* __restrict__ off, int* __restrict__ cursor, int n) {
    __shared__ int sd[256];
    int b = blockIdx.x, t = threadIdx.x;
    int i0 = b * 1024 + 4 * t;
    int c0 = 0, c1 = 0, c2 = 0, c3 = 0;
    if (i0 + 3 < n) {
        int4 q = *(const int4*)(cnt + i0);
        c0 = q.x; c1 = q.y; c2 = q.z; c3 = q.w;
    } else {
        if (i0     < n) c0 = cnt[i0];
        if (i0 + 1 < n) c1 = cnt[i0 + 1];
        if (i0 + 2 < n) c2 = cnt[i0 + 2];
        if (i0 + 3 < n) c3 = cnt[i0 + 3];
    }
    int s = c0 + c1 + c2 + c3;
    sd[t] = s;
    __syncthreads();
    for (int d = 1; d < 256; d <<= 1) {
        int w = (t >= d) ? sd[t - d] : 0;
        __syncthreads();
        sd[t] += w;
        __syncthreads();
    }
    int o0 = sd[t] - s + bbase[b];
    int o1 = o0 + c0, o2 = o1 + c1, o3 = o2 + c2;
    if (i0 + 3 < n) {
        int4 q = make_int4(o0, o1, o2, o3);
        *(int4*)(off + i0) = q;
        *(int4*)(cursor + i0) = q;
    } else {
        if (i0     < n) { off[i0]     = o0; cursor[i0]     = o0; }
        if (i0 + 1 < n) { off[i0 + 1] = o1; cursor[i0 + 1] = o1; }
        if (i0 + 2 < n) { off[i0 + 2] = o2; cursor[i0 + 2] = o2; }
        if (i0 + 3 < n) { off[i0 + 3] = o3; cursor[i0 + 3] = o3; }
    }
}

// 4 edges per thread (int4 reads of src/dst/et).
__global__ void k_scatter(const int* __restrict__ src, const int* __restrict__ dst,
                          const int* __restrict__ et, int* __restrict__ cursor,
                          unsigned int* __restrict__ bucket, int e4) {
    int i = blockIdx.x * blockDim.x + threadIdx.x;
    if (i < e4) {
        int4 s = ((const int4*)src)[i];
        int4 d = ((const int4*)dst)[i];
        int4 t = ((const int4*)et)[i];
        int p0 = atomicAdd(&cursor[d.x], 1);
        bucket[p0] = (unsigned int)s.x | ((unsigned int)t.x << 16);
        int p1 = atomicAdd(&cursor[d.y], 1);
        bucket[p1] = (unsigned int)s.y | ((unsigned int)t.y << 16);
        int p2 = atomicAdd(&cursor[d.z], 1);
        bucket[p2] = (unsigned int)s.z | ((unsigned int)t.z << 16);
        int p3 = atomicAdd(&cursor[d.w], 1);
        bucket[p3] = (unsigned int)s.w | ((unsigned int)t.w << 16);
    }
}

// One wave per NPW nodes; lane = feature index.
// Phase A: S_h,S_r,S_hr per node; j-unroll x8 => 16 gathers in flight.
// Phase B: out[v][lane] = sum_k x[v][k]*Wc[k][lane]; kk-unroll capped at 8
//          (full unroll spilled in R3: VGPR=256, 2.8 GB scratch, 4 ms).
// launch_bounds(256,8): R5 sat at 4 blocks/CU (occ 50%, VALUBusy 37%,
// latency-bound); VGPR 44 fits the 64-reg budget for 8 waves/SIMD.
__global__ __launch_bounds__(256, 8) void k_main(
    const float* __restrict__ feat, const float* __restrict__ rel,
    const float* __restrict__ wc, const int* __restrict__ off,
    const unsigned int* __restrict__ bucket,
    float* __restrict__ out, int n_nodes) {

    const int lane = threadIdx.x & 63;
    const int wid  = threadIdx.x >> 6;
    const int node0 = (blockIdx.x * 4 + wid) * NPW;

    float aH[NPW], aR[NPW], aHR[NPW], fv[NPW], acc[NPW];
#pragma unroll
    for (int n = 0; n < NPW; ++n) { aH[n]=0.f; aR[n]=0.f; aHR[n]=0.f; fv[n]=0.f; acc[n]=0.f; }

#pragma unroll
    for (int n = 0; n < NPW; ++n) {
        int v = node0 + n;
        if (v < n_nodes) {
            int o0 = off[v], o1 = off[v + 1];
            float sH = 0.f, sR = 0.f, sHR = 0.f;
            for (int p = o0; p < o1; p += 64) {
                int m = o1 - p; if (m > 64) m = 64;
                unsigned int pk = (lane < m) ? bucket[p + lane] : 0u;
                int j = 0;
                for (; j + 8 <= m; j += 8) {
                    unsigned int u0 = __shfl(pk, j);
                    unsigned int u1 = __shfl(pk, j + 1);
                    unsigned int u2 = __shfl(pk, j + 2);
                    unsigned int u3 = __shfl(pk, j + 3);
                    unsigned int u4 = __shfl(pk, j + 4);
                    unsigned int u5 = __shfl(pk, j + 5);
                    unsigned int u6 = __shfl(pk, j + 6);
                    unsigned int u7 = __shfl(pk, j + 7);
                    float h0 = feat[(int)(u0 & 0xFFFFu) * F + lane];
                    float r0 = rel[(int)(u0 >> 16) * F + lane];
                    float h1 = feat[(int)(u1 & 0xFFFFu) * F + lane];
                    float r1 = rel[(int)(u1 >> 16) * F + lane];
                    float h2 = feat[(int)(u2 & 0xFFFFu) * F + lane];
                    float r2 = rel[(int)(u2 >> 16) * F + lane];
                    float h3 = feat[(int)(u3 & 0xFFFFu) * F + lane];
                    float r3 = rel[(int)(u3 >> 16) * F + lane];
                    float h4 = feat[(int)(u4 & 0xFFFFu) * F + lane];
                    float r4 = rel[(int)(u4 >> 16) * F + lane];
                    float h5 = feat[(int)(u5 & 0xFFFFu) * F + lane];
                    float r5 = rel[(int)(u5 >> 16) * F + lane];
                    float h6 = feat[(int)(u6 & 0xFFFFu) * F + lane];
                    float r6 = rel[(int)(u6 >> 16) * F + lane];
                    float h7 = feat[(int)(u7 & 0xFFFFu) * F + lane];
                    float r7 = rel[(int)(u7 >> 16) * F + lane];
                    sH += ((h0 + h1) + (h2 + h3)) + ((h4 + h5) + (h6 + h7));
                    sR += ((r0 + r1) + (r2 + r3)) + ((r4 + r5) + (r6 + r7));
                    sHR += h0 * r0 + h1 * r1 + h2 * r2 + h3 * r3
                         + h4 * r4 + h5 * r5 + h6 * r6 + h7 * r7;
                }
                for (; j < m; ++j) {
                    unsigned int u = __shfl(pk, j);
                    float h = feat[(int)(u & 0xFFFFu) * F + lane];
                    float r = rel[(int)(u >> 16) * F + lane];
                    sH += h; sR += r; sHR += h * r;
                }
            }
            int deg = o1 - o0;
            float inv = (deg > 0) ? 1.0f / (float)deg : 1.0f;
            aH[n] = sH * inv; aR[n] = sR * inv; aHR[n] = sHR * inv;
            fv[n] = feat[v * F + lane];
        }
    }

#pragma unroll 8
    for (int kk = 0; kk < 64; ++kk) {
        float w0 = wc[kk * F + lane];
        float w1 = wc[(64 + kk) * F + lane];
        float w2 = wc[(128 + kk) * F + lane];
        float w3 = wc[(192 + kk) * F + lane];
#pragma unroll
        for (int n = 0; n < NPW; ++n) {
            acc[n] += __shfl(aH[n], kk) * w0 + __shfl(aR[n], kk) * w1
                    + __shfl(aHR[n], kk) * w2 + __shfl(fv[n], kk) * w3;
        }
    }

#pragma unroll
    for (int n = 0; n < NPW; ++n) {
        int v = node0 + n;
        if (v < n_nodes) out[v * F + lane] = acc[n];
    }
}

extern "C" void kernel_launch(void* const* d_in, const int* in_sizes, int n_in,
                              void* d_out, int out_size, void* d_ws, size_t ws_size,
                              hipStream_t stream) {
    const float* feat = (const float*)d_in[0];
    const float* rel  = (const float*)d_in[1];
    const float* wn   = (const float*)d_in[2];
    const float* lw   = (const float*)d_in[3];
    const int* src = (const int*)d_in[4];
    const int* dst = (const int*)d_in[5];
    const int* et  = (const int*)d_in[6];
    float* out = (float*)d_out;

    const int N = in_sizes[0] / F;
    const int E = in_sizes[4];
    const int E4 = E / 4;               // E=800000 divisible by 4
    const int NB = (N + 1023) / 1024;   // 49 for N=50000

    int* ws = (int*)d_ws;
    int* cnt             = ws;                            // N
    int* off             = cnt + N;                       // N+1
    int* cursor          = off + N + 1;                   // N
    int* bsum            = cursor + N;                    // NB
    int* bbase           = bsum + NB;                     // NB
    unsigned int* bucket = (unsigned int*)(bbase + NB);   // E
    float* wc            = (float*)(bucket + E);          // 16384

    hipMemsetAsync(cnt, 0, (size_t)N * sizeof(int), stream);
    k_prep<<<64, 256, 0, stream>>>(wn, lw, wc);
    k_hist<<<(E4 + 255) / 256, 256, 0, stream>>>(dst, cnt, E4);
    k_bsum<<<NB, 256, 0, stream>>>(cnt, bsum, N);
    k_bscan<<<1, 64, 0, stream>>>(bsum, bbase, off, NB, N);
    k_off<<<NB, 256, 0, stream>>>(cnt, bbase, off, cursor, N);
    k_scatter<<<(E4 + 255) / 256, 256, 0, stream>>>(src, dst, et, cursor, bucket, E4);
    int blocks = (N + NPW * 4 - 1) / (NPW * 4);   // 8 nodes/block
    k_main<<<blocks, 256, 0, stream>>>(feat, rel, wc, off, bucket, out, N);
}

// Round 7
// 241.685 us; speedup vs baseline: 17.8377x; 1.3151x over previous
//
#include <hip/hip_runtime.h>
#include <hip/hip_bf16.h>

#define F 64
#define NPW 2   // nodes per wave; 4 waves/block -> 8 nodes/block

// Combined weight Wc[256][64] f32 (factorization of concat([h+r,h*r,h,r])@W):
//   rows 0..63  : W0+W2   (multiplies mean_h)
//   rows 64..127: W0+W3   (multiplies mean_r)
//   rows 128..191: W1     (multiplies mean_{h*r})
//   rows 192..255: loop_weight (multiplies feat)
__global__ void k_prep(const float* __restrict__ wn, const float* __restrict__ lw,
                       float* __restrict__ wc) {
    int i = blockIdx.x * 256 + threadIdx.x;   // 0..16383
    int k = i >> 6, j = i & 63;
    float v;
    if (k < 64)
        v = wn[k * 64 + j] + wn[(128 + k) * 64 + j];
    else if (k < 128)
        v = wn[(k - 64) * 64 + j] + wn[(k + 128) * 64 + j];
    else if (k < 192)
        v = wn[(k - 64) * 64 + j];            // W1 row (k-128) = wn row 64+(k-128)
    else
        v = lw[(k - 192) * 64 + j];
    wc[i] = v;
}

// 4 edges per thread (int4).
__global__ void k_hist(const int* __restrict__ dst, int* __restrict__ cnt, int e4) {
    int i = blockIdx.x * blockDim.x + threadIdx.x;
    if (i < e4) {
        int4 d = ((const int4*)dst)[i];
        atomicAdd(&cnt[d.x], 1);
        atomicAdd(&cnt[d.y], 1);
        atomicAdd(&cnt[d.z], 1);
        atomicAdd(&cnt[d.w], 1);
    }
}

// --- coalesced 3-kernel scan ---
__global__ void k_bsum(const int* __restrict__ cnt, int* __restrict__ bsum, int n) {
    __shared__ int sd[256];
    int b = blockIdx.x, t = threadIdx.x;
    int base = b * 1024;
    int s = 0;
#pragma unroll
    for (int k = 0; k < 4; ++k) {
        int i = base + k * 256 + t;
        if (i < n) s += cnt[i];
    }
    sd[t] = s;
    __syncthreads();
    for (int st = 128; st > 0; st >>= 1) {
        if (t < st) sd[t] += sd[t + st];
        __syncthreads();
    }
    if (t == 0) bsum[b] = sd[0];
}

__global__ void k_bscan(const int* __restrict__ bsum, int* __restrict__ bbase,
                        int* __restrict__ off, int nb, int n) {
    int lane = threadIdx.x;
    if (nb <= 64) {
        int own = (lane < nb) ? bsum[lane] : 0;
        int v = own;
        for (int d = 1; d < 64; d <<= 1) {
            int w = __shfl_up(v, d);
            if (lane >= d) v += w;
        }
        if (lane < nb) bbase[lane] = v - own;   // exclusive
        if (lane == 63) off[n] = v;             // grand total
    } else if (lane == 0) {                     // safety fallback
        int run = 0;
        for (int i = 0; i < nb; ++i) { bbase[i] = run; run += bsum[i]; }
        off[n] = run;
    }
}

__global__ void k_off(const int* __restrict__ cnt, const int* __restrict__ bbase,
                      int* __restrict__ off, int* __restrict__ cursor, int n) {
    __shared__ int sd[256];
    int b = blockIdx.x, t = threadIdx.x;
    int i0 = b * 1024 + 4 * t;
    int c0 = 0, c1 = 0, c2 = 0, c3 = 0;
    if (i0 + 3 < n) {
        int4 q = *(const int4*)(cnt + i0);
        c0 = q.x; c1 = q.y; c2 = q.z; c3 = q.w;
    } else {
        if (i0     < n) c0 = cnt[i0];
        if (i0 + 1 < n) c1 = cnt[i0 + 1];
        if (i0 + 2 < n) c2 = cnt[i0 + 2];
        if (i0 + 3 < n) c3 = cnt[i0 + 3];
    }
    int s = c0 + c1 + c2 + c3;
    sd[t] = s;
    __syncthreads();
    for (int d = 1; d < 256; d <<= 1) {
        int w = (t >= d) ? sd[t - d] : 0;
        __syncthreads();
        sd[t] += w;
        __syncthreads();
    }
    int o0 = sd[t] - s + bbase[b];
    int o1 = o0 + c0, o2 = o1 + c1, o3 = o2 + c2;
    if (i0 + 3 < n) {
        int4 q = make_int4(o0, o1, o2, o3);
        *(int4*)(off + i0) = q;
        *(int4*)(cursor + i0) = q;
    } else {
        if (i0     < n) { off[i0]     = o0; cursor[i0]     = o0; }
        if (i0 + 1 < n) { off[i0 + 1] = o1; cursor[i0 + 1] = o1; }
        if (i0 + 2 < n) { off[i0 + 2] = o2; cursor[i0 + 2] = o2; }
        if (i0 + 3 < n) { off[i0 + 3] = o3; cursor[i0 + 3] = o3; }
    }
}

// 4 edges per thread.
__global__ void k_scatter(const int* __restrict__ src, const int* __restrict__ dst,
                          const int* __restrict__ et, int* __restrict__ cursor,
                          unsigned int* __restrict__ bucket, int e4) {
    int i = blockIdx.x * blockDim.x + threadIdx.x;
    if (i < e4) {
        int4 s = ((const int4*)src)[i];
        int4 d = ((const int4*)dst)[i];
        int4 t = ((const int4*)et)[i];
        int p0 = atomicAdd(&cursor[d.x], 1);
        bucket[p0] = (unsigned int)s.x | ((unsigned int)t.x << 16);
        int p1 = atomicAdd(&cursor[d.y], 1);
        bucket[p1] = (unsigned int)s.y | ((unsigned int)t.y << 16);
        int p2 = atomicAdd(&cursor[d.z], 1);
        bucket[p2] = (unsigned int)s.z | ((unsigned int)t.z << 16);
        int p3 = atomicAdd(&cursor[d.w], 1);
        bucket[p3] = (unsigned int)s.w | ((unsigned int)t.w << 16);
    }
}

// One wave per NPW nodes; lane = feature index.
// Phase A: edge indices scalarized via v_readlane (wave-uniform j) so gather
//          loads are saddr-form, 1 VGPR each -> 16 truly in flight.
//          (R6 lesson: VGPR=24 meant the compiler serialized the gathers;
//          R5/R6 both sat at 169us = same waves x inflight product.)
// Phase B: X[256] per node staged in LDS; same-address ds_read_b128 broadcast
//          (no bank conflicts, no barrier - same-wave producer/consumer).
__global__ __launch_bounds__(256, 8) void k_main(
    const float* __restrict__ feat, const float* __restrict__ rel,
    const float* __restrict__ wc, const int* __restrict__ off,
    const unsigned int* __restrict__ bucket,
    float* __restrict__ out, int n_nodes) {

    __shared__ float xs[4 * NPW * 256];   // 8 KB: per-wave node vectors

    const int lane = threadIdx.x & 63;
    const int wid  = threadIdx.x >> 6;
    const int node0 = (blockIdx.x * 4 + wid) * NPW;

#pragma unroll
    for (int n = 0; n < NPW; ++n) {
        float* X = &xs[(wid * NPW + n) * 256];
        int v = node0 + n;
        float sH = 0.f, sR = 0.f, sHR = 0.f, f0 = 0.f;
        if (v < n_nodes) {
            int o0 = off[v], o1 = off[v + 1];
            for (int p = o0; p < o1; p += 64) {
                int m = o1 - p; if (m > 64) m = 64;
                unsigned int pk = (lane < m) ? bucket[p + lane] : 0u;
                int j = 0;
                for (; j + 8 <= m; j += 8) {
                    float h[8], r[8];
#pragma unroll
                    for (int q = 0; q < 8; ++q) {
                        int u = __builtin_amdgcn_readlane((int)pk, j + q);
                        h[q] = feat[((u & 0xFFFF) << 6) + lane];
                        r[q] = rel[((((unsigned)u) >> 16) << 6) + lane];
                    }
#pragma unroll
                    for (int q = 0; q < 8; ++q) {
                        sH += h[q]; sR += r[q]; sHR += h[q] * r[q];
                    }
                }
                for (; j < m; ++j) {
                    int u = __builtin_amdgcn_readlane((int)pk, j);
                    float h = feat[((u & 0xFFFF) << 6) + lane];
                    float r = rel[((((unsigned)u) >> 16) << 6) + lane];
                    sH += h; sR += r; sHR += h * r;
                }
            }
            int deg = o1 - o0;
            float inv = (deg > 0) ? 1.0f / (float)deg : 1.0f;
            sH *= inv; sR *= inv; sHR *= inv;
            f0 = feat[v * F + lane];
        }
        X[lane]       = sH;
        X[64 + lane]  = sR;
        X[128 + lane] = sHR;
        X[192 + lane] = f0;
    }

    float acc[NPW];
#pragma unroll
    for (int n = 0; n < NPW; ++n) acc[n] = 0.f;

#pragma unroll 4
    for (int k4 = 0; k4 < 64; ++k4) {
        float w0 = wc[(4 * k4 + 0) * 64 + lane];
        float w1 = wc[(4 * k4 + 1) * 64 + lane];
        float w2 = wc[(4 * k4 + 2) * 64 + lane];
        float w3 = wc[(4 * k4 + 3) * 64 + lane];
#pragma unroll
        for (int n = 0; n < NPW; ++n) {
            const float4 xv = *(const float4*)&xs[(wid * NPW + n) * 256 + 4 * k4];
            acc[n] += xv.x * w0 + xv.y * w1 + xv.z * w2 + xv.w * w3;
        }
    }

#pragma unroll
    for (int n = 0; n < NPW; ++n) {
        int v = node0 + n;
        if (v < n_nodes) out[v * F + lane] = acc[n];
    }
}

extern "C" void kernel_launch(void* const* d_in, const int* in_sizes, int n_in,
                              void* d_out, int out_size, void* d_ws, size_t ws_size,
                              hipStream_t stream) {
    const float* feat = (const float*)d_in[0];
    const float* rel  = (const float*)d_in[1];
    const float* wn   = (const float*)d_in[2];
    const float* lw   = (const float*)d_in[3];
    const int* src = (const int*)d_in[4];
    const int* dst = (const int*)d_in[5];
    const int* et  = (const int*)d_in[6];
    float* out = (float*)d_out;

    const int N = in_sizes[0] / F;
    const int E = in_sizes[4];
    const int E4 = E / 4;               // E=800000 divisible by 4
    const int NB = (N + 1023) / 1024;   // 49 for N=50000

    int* ws = (int*)d_ws;
    int* cnt             = ws;                            // N
    int* off             = cnt + N;                       // N+1
    int* cursor          = off + N + 1;                   // N
    int* bsum            = cursor + N;                    // NB
    int* bbase           = bsum + NB;                     // NB
    unsigned int* bucket = (unsigned int*)(bbase + NB);   // E
    float* wc            = (float*)(bucket + E);          // 16384

    hipMemsetAsync(cnt, 0, (size_t)N * sizeof(int), stream);
    k_prep<<<64, 256, 0, stream>>>(wn, lw, wc);
    k_hist<<<(E4 + 255) / 256, 256, 0, stream>>>(dst, cnt, E4);
    k_bsum<<<NB, 256, 0, stream>>>(cnt, bsum, N);
    k_bscan<<<1, 64, 0, stream>>>(bsum, bbase, off, NB, N);
    k_off<<<NB, 256, 0, stream>>>(cnt, bbase, off, cursor, N);
    k_scatter<<<(E4 + 255) / 256, 256, 0, stream>>>(src, dst, et, cursor, bucket, E4);
    int blocks = (N + NPW * 4 - 1) / (NPW * 4);   // 8 nodes/block
    k_main<<<blocks, 256, 0, stream>>>(feat, rel, wc, off, bucket, out, N);
}